// Round 15
// baseline (373.136 us; speedup 1.0000x reference)
//
#include <hip/hip_runtime.h>

typedef _Float16 half2v __attribute__((ext_vector_type(2)));
typedef _Float16 half4v __attribute__((ext_vector_type(4)));
typedef _Float16 half8v __attribute__((ext_vector_type(8)));

#define HH 1024
#define OHW 256
#define TH 16
#define TW 32
#define NR 80        // input-tile rows
#define NCH 18       // data chunks (8 halves) per row = 144 cols
#define ROWH 160     // padded row stride in halves (20 chunks)
#define NTHREADS 256
#define ESPAN 528
#define ECHUNK (ESPAN/4)

#if defined(__has_builtin)
#  if __has_builtin(__builtin_amdgcn_fdot2)
#    define HAS_FDOT2 1
#  endif
#endif
#ifndef HAS_FDOT2
#  define HAS_FDOT2 0
#endif

__constant__ float DEC12c[12] = {
  -1.20162964e-04f,  1.615524292e-03f, -1.0385513306e-02f,  4.3619155884e-02f,
  -1.45397186478e-01f, 6.10668182370e-01f, 6.10668182370e-01f, -1.45397186478e-01f,
   4.3619155884e-02f, -1.0385513306e-02f,  1.615524292e-03f, -1.20162964e-04f
};

__device__ __forceinline__ int clampi(int v) { return v < 0 ? 0 : (v > HH - 1 ? HH - 1 : v); }

__device__ __forceinline__ int swzc(int c, int r) {
  return c ^ ((c >> 3) & 1) ^ ((r >> 2) & 3);
}

__device__ __forceinline__ half2v mk2(_Float16 a, _Float16 b) {
  half2v r; r.x = a; r.y = b; return r;
}

template<int J>   // J = half2 index 0..11 within 3 half8 regs
__device__ __forceinline__ half2v sel3(half8v a, half8v b, half8v c) {
  constexpr int V = J >> 2, E = J & 3;
  const half8v s = (V == 0) ? a : (V == 1) ? b : c;
  return mk2(s[2 * E], s[2 * E + 1]);
}
template<int E>
__device__ __forceinline__ half2v g2(half8v v) { return mk2(v[2 * E], v[2 * E + 1]); }

__device__ __forceinline__ float dot2acc(half2v w, half2v k, float acc) {
#if HAS_FDOT2
  return __builtin_amdgcn_fdot2(w, k, acc, false);
#else
  return acc + (float)w.x * (float)k.x + (float)w.y * (float)k.y;
#endif
}

// =================== aux kernel: ckbuild + edgefix + cornerfix ===================
// grid.x = 32 (ckbuild) + 384 (edgefix) + 288 (cornerfix) = 704, block 128
// Edge sections SKIP the 9 corner points per image; cornerfix blocks own them
// exclusively (no intra-dispatch write races — blocks are unordered).
__global__ __launch_bounds__(128) void dgp_aux(
    const float* __restrict__ inp, const float* __restrict__ mtfp,
    const int* __restrict__ rp, const int* __restrict__ cp,
    _Float16* __restrict__ ckg, float* __restrict__ outg) {
  __shared__ __align__(16) unsigned char smem[45056];
  float* tile = (float*)smem;                          // 20*528 f32 = 42240 B
  float* ck   = (float*)(smem + 42240);                // 400 f32
  float* kva  = (float*)(smem + 42240 + 1600);         // 180 f32
  float* mlds = (float*)(smem + 42240 + 1600 + 720);   // 81 f32
  float* avs  = (float*)(smem + 42240 + 1600 + 720 + 324);        // 12
  float* bvs  = (float*)(smem + 42240 + 1600 + 720 + 324 + 48);   // 12

  const int tid = threadIdx.x;
  const int b = blockIdx.x;

  if (b < 32) {
    // ---------------- section 1: combined-kernel build -> ckg ----------------
    const int bz = b;
    const int chC = bz & 7;
    const int rv = rp[bz], cv = cp[bz];
    const int rf = rv & 1, cf = cv & 1;

    if (tid < 12)       avs[tid] = rf ? DEC12c[tid] : (tid == 6 ? 1.f : 0.f);
    else if (tid < 24)  bvs[tid - 12] = cf ? DEC12c[tid - 12] : (tid - 12 == 6 ? 1.f : 0.f);
    else if (tid < 105) { const int m = tid - 24; mlds[m] = mtfp[m * 8 + chC]; }
    __syncthreads();

    for (int i = tid; i < 180; i += 128) {
      const int S = i / 9, v = i - S * 9;
      const int plo = (S - 8 > 0) ? S - 8 : 0, phi = (S < 11) ? S : 11;
      float s1 = 0.f;
      for (int p = plo; p <= phi; ++p) s1 += avs[p] * mlds[(S - p) * 9 + v];
      kva[i] = s1;
    }
    __syncthreads();

    half2v* out2 = (half2v*)ckg;
    for (int i = tid; i < 200; i += 128) {
      const int S = i / 10, m = i - S * 10;
      float s[2];
      #pragma unroll
      for (int h = 0; h < 2; ++h) {
        const int T = 2 * m + h;
        const int qlo = (T - 8 > 0) ? T - 8 : 0, qhi = (T < 11) ? T : 11;
        float acc = 0.f;
        for (int q = qlo; q <= qhi; ++q) acc += bvs[q] * kva[S * 9 + (T - q)];
        s[h] = acc;
      }
      out2[bz * 320 + S * 16 + m] = mk2((_Float16)s[0], (_Float16)s[1]);
    }
  } else if (b < 416) {
    // ---------------- section 2: edge fixup (rows/cols {0,1,255}, minus corners) ----------------
    const int e = b - 32;
    const int bx = e & 1;
    const int t = e >> 1;
    const int segi6 = t % 6;
    const int bz = t / 6;
    const bool isRow = (segi6 < 3);
    const int segi = isRow ? segi6 : segi6 - 3;
    const int fixedo = (segi == 2) ? 255 : segi;
    const int chC = bz & 7;
    const int rv = rp[bz], cv = cp[bz];
    const int ri = rv >> 1, rf = rv & 1, ci = cv >> 1, cf = cv & 1;

    if (tid < 12) {
      float av = rf ? DEC12c[tid] : (tid == 6 ? 1.f : 0.f);
      if (isRow) {
        const int xi = (2 + 4 * fixedo - ri) - 6 + tid;
        if (xi < 0 || xi >= HH) av = 0.f;
      }
      avs[tid] = av;
    } else if (tid < 24) {
      const int q = tid - 12;
      float bv = cf ? DEC12c[q] : (q == 6 ? 1.f : 0.f);
      if (!isRow) {
        const int xj = (2 + 4 * fixedo - ci) - 6 + q;
        if (xj < 0 || xj >= HH) bv = 0.f;
      }
      bvs[q] = bv;
    } else if (tid < 105) {
      const int m = tid - 24; mlds[m] = mtfp[m * 8 + chC];
    }
    __syncthreads();

    for (int i = tid; i < 180; i += 128) {
      const int S = i / 9, v = i - S * 9;
      const int plo = (S - 8 > 0) ? S - 8 : 0, phi = (S < 11) ? S : 11;
      float s1 = 0.f;
      for (int p = plo; p <= phi; ++p) s1 += avs[p] * mlds[(S - p) * 9 + v];
      kva[i] = s1;
    }
    __syncthreads();
    for (int i = tid; i < 400; i += 128) {
      const int S = i / 20, T = i - S * 20;
      const int qlo = (T - 8 > 0) ? T - 8 : 0, qhi = (T < 11) ? T : 11;
      float s1 = 0.f;
      for (int q = qlo; q <= qhi; ++q) s1 += bvs[q] * kva[S * 9 + (T - q)];
      ck[i] = s1;
    }

    const float* src = inp + ((size_t)bz << 20);
    if (isRow) {
      const int R0 = (2 + 4 * fixedo - ri) - 10;
      const int C0c = 512 * bx - 8 - ci;
      for (int i = tid; i < 20 * ECHUNK; i += 128) {
        const int rr = i / ECHUNK, jc = i - rr * ECHUNK;
        const float* grow = src + (clampi(R0 + rr) << 10);
        const int c0 = C0c + 4 * jc;
        float4 v;
        v.x = grow[clampi(c0 + 0)];
        v.y = grow[clampi(c0 + 1)];
        v.z = grow[clampi(c0 + 2)];
        v.w = grow[clampi(c0 + 3)];
        *(float4*)(tile + rr * ESPAN + 4 * jc) = v;
      }
    } else {
      const int Cw0 = (2 + 4 * fixedo - ci) - 10;
      const int Rr0 = 512 * bx - 8 - ri;
      for (int i = tid; i < 20 * ESPAN; i += 128) {
        const int T = i / ESPAN, rr = i - T * ESPAN;
        tile[T * ESPAN + rr] = src[(clampi(Rr0 + rr) << 10) + clampi(Cw0 + T)];
      }
    }
    __syncthreads();

    float acc = 0.f;
    #pragma unroll 4
    for (int L = 0; L < 20; ++L) {
      const float* wp = tile + L * ESPAN + 4 * tid;
      float w[20];
      #pragma unroll
      for (int j = 0; j < 5; ++j) {
        const float4 v = *(const float4*)(wp + 4 * j);
        w[4 * j] = v.x; w[4 * j + 1] = v.y; w[4 * j + 2] = v.z; w[4 * j + 3] = v.w;
      }
      if (isRow) {
        #pragma unroll
        for (int ee = 0; ee < 20; ++ee) acc += ck[L * 20 + ee] * w[ee];
      } else {
        #pragma unroll
        for (int ee = 0; ee < 20; ++ee) acc += ck[ee * 20 + L] * w[ee];
      }
    }

    int oi, oj;
    if (isRow) { oi = fixedo; oj = 128 * bx + tid; }
    else       { oj = fixedo; oi = 128 * bx + tid; }
    const int ov = isRow ? oj : oi;   // the varying coordinate
    if (ov != 0 && ov != 1 && ov != 255)   // corners owned by cornerfix blocks
      outg[((size_t)bz * OHW + oi) * OHW + oj] = acc;
  } else {
    // ---------------- section 3: corner fixup (9 points/image) ----------------
    const int c = b - 416;
    const int bi = c % 3;
    const int t = c / 3;
    const int bj = t % 3;
    const int bz = t / 3;
    const int oi = (bi == 2) ? 255 : bi;
    const int oj = (bj == 2) ? 255 : bj;
    const int chC = bz & 7;
    const int rv = rp[bz], cv = cp[bz];
    const int ri = rv >> 1, rf = rv & 1, ci = cv >> 1, cf = cv & 1;

    if (tid < 12)       avs[tid] = rf ? DEC12c[tid] : (tid == 6 ? 1.f : 0.f);
    else if (tid < 24)  bvs[tid - 12] = cf ? DEC12c[tid - 12] : (tid - 12 == 6 ? 1.f : 0.f);
    for (int m = tid; m < 81; m += 128) mlds[m] = mtfp[m * 8 + chC];
    __syncthreads();
    if (tid >= 64) return;

    const int Ri = 2 + 4 * oi - ri;
    const int Cj = 2 + 4 * oj - ci;
    const float* src = inp + ((size_t)bz << 20);

    float acc = 0.f;
    for (int pair = tid; pair < 144; pair += 64) {
      const int p = pair / 12, q = pair - 12 * (pair / 12);
      const int xi = Ri - 6 + p, xj = Cj - 6 + q;
      if (xi < 0 || xi >= HH || xj < 0 || xj >= HH) continue;
      const float ab = avs[p] * bvs[q];
      if (ab == 0.f) continue;
      float s = 0.f;
      #pragma unroll
      for (int u = 0; u < 9; ++u) {
        const float* grow = src + (clampi(xi - 4 + u) << 10);
        #pragma unroll
        for (int v = 0; v < 9; ++v) s += mlds[u * 9 + v] * grow[clampi(xj - 4 + v)];
      }
      acc += ab * s;
    }
    #pragma unroll
    for (int off = 32; off > 0; off >>= 1) acc += __shfl_down(acc, off);
    if (tid == 0) outg[((size_t)bz * OHW + oi) * OHW + oj] = acc;
  }
}

// =================== main kernel: r12 grid-stride staging + guarded boundary stores ===================
__global__ __launch_bounds__(NTHREADS, 6) void dgp_main(
    const float* __restrict__ inp, const int* __restrict__ rp,
    const int* __restrict__ cp, const _Float16* __restrict__ ckg,
    float* __restrict__ outg) {
  __shared__ __align__(64) _Float16 tile[NR * ROWH];   // 25600 B

  const int tid = threadIdx.x;
  const int bxt = blockIdx.x, by = blockIdx.y, bz = blockIdx.z;
  const int rv = rp[bz], cv = cp[bz];
  const int ri = rv >> 1, ci = cv >> 1;
  const int R0 = 4 * TH * by - 8 - ri;
  const int C0 = 4 * TW * bxt - 8 - ci;

  // stage 80x144 tile as f16, swizzled chunks; per-chunk interior fast path
  const float* src = inp + ((size_t)bz << 20);
  for (int idx = tid; idx < NR * NCH; idx += NTHREADS) {
    const int rr = idx / 18, g = idx - 18 * rr;
    const float* grow = src + (clampi(R0 + rr) << 10);
    const int c0 = C0 + 8 * g;
    float v[8];
    if (c0 >= 0 && c0 + 7 <= HH - 1) {
      __builtin_memcpy(v, grow + c0, 32);
    } else {
      #pragma unroll
      for (int i = 0; i < 8; ++i) v[i] = grow[clampi(c0 + i)];
    }
    _Float16 h[8];
    #pragma unroll
    for (int i = 0; i < 8; ++i) h[i] = (_Float16)v[i];
    __builtin_memcpy(tile + rr * ROWH + (swzc(g, rr) << 3), h, 16);
  }
  __syncthreads();

  const int ty = tid >> 4;   // 0..15 output row
  const int tx = tid & 15;   // 0..15 -> 2 outputs at cols 2tx, 2tx+1
  const int rbase = 4 * ty;
  const size_t kbase = (size_t)bz * 640;

  float a0e = 0.f, a0o = 0.f, a1e = 0.f, a1o = 0.f;

#define DOT_STEP(s_) do {                                                \
    const int r_ = rbase + (s_);                                         \
    const _Float16* rp_ = tile + r_ * ROWH;                              \
    const half8v w0 = *(const half8v*)(rp_ + (swzc(tx + 0, r_) << 3));   \
    const half8v w1 = *(const half8v*)(rp_ + (swzc(tx + 1, r_) << 3));   \
    const half8v w2 = *(const half8v*)(rp_ + (swzc(tx + 2, r_) << 3));   \
    const _Float16* kp_ = ckg + kbase + (s_) * 32;                       \
    const half8v K0 = *(const half8v*)(kp_);                             \
    const half8v K1 = *(const half8v*)(kp_ + 8);                         \
    const half4v K2 = *(const half4v*)(kp_ + 16);                        \
    a0e = dot2acc(sel3<0>(w0, w1, w2), g2<0>(K0), a0e);                  \
    a0o = dot2acc(sel3<1>(w0, w1, w2), g2<1>(K0), a0o);                  \
    a0e = dot2acc(sel3<2>(w0, w1, w2), g2<2>(K0), a0e);                  \
    a0o = dot2acc(sel3<3>(w0, w1, w2), g2<3>(K0), a0o);                  \
    a0e = dot2acc(sel3<4>(w0, w1, w2), g2<0>(K1), a0e);                  \
    a0o = dot2acc(sel3<5>(w0, w1, w2), g2<1>(K1), a0o);                  \
    a0e = dot2acc(sel3<6>(w0, w1, w2), g2<2>(K1), a0e);                  \
    a0o = dot2acc(sel3<7>(w0, w1, w2), g2<3>(K1), a0o);                  \
    a0e = dot2acc(sel3<8>(w0, w1, w2), mk2(K2[0], K2[1]), a0e);          \
    a0o = dot2acc(sel3<9>(w0, w1, w2), mk2(K2[2], K2[3]), a0o);          \
    a1e = dot2acc(sel3<2>(w0, w1, w2), g2<0>(K0), a1e);                  \
    a1o = dot2acc(sel3<3>(w0, w1, w2), g2<1>(K0), a1o);                  \
    a1e = dot2acc(sel3<4>(w0, w1, w2), g2<2>(K0), a1e);                  \
    a1o = dot2acc(sel3<5>(w0, w1, w2), g2<3>(K0), a1o);                  \
    a1e = dot2acc(sel3<6>(w0, w1, w2), g2<0>(K1), a1e);                  \
    a1o = dot2acc(sel3<7>(w0, w1, w2), g2<1>(K1), a1o);                  \
    a1e = dot2acc(sel3<8>(w0, w1, w2), g2<2>(K1), a1e);                  \
    a1o = dot2acc(sel3<9>(w0, w1, w2), g2<3>(K1), a1o);                  \
    a1e = dot2acc(sel3<10>(w0, w1, w2), mk2(K2[0], K2[1]), a1e);         \
    a1o = dot2acc(sel3<11>(w0, w1, w2), mk2(K2[2], K2[3]), a1o);         \
  } while (0)

  DOT_STEP(0);  DOT_STEP(1);  DOT_STEP(2);  DOT_STEP(3);  DOT_STEP(4);
  DOT_STEP(5);  DOT_STEP(6);  DOT_STEP(7);  DOT_STEP(8);  DOT_STEP(9);
  DOT_STEP(10); DOT_STEP(11); DOT_STEP(12); DOT_STEP(13); DOT_STEP(14);
  DOT_STEP(15); DOT_STEP(16); DOT_STEP(17); DOT_STEP(18); DOT_STEP(19);
#undef DOT_STEP

  const int oi = TH * by + ty;
  const int oj0 = TW * bxt + 2 * tx;
  const float v0 = a0e + a0o;
  const float v1 = a1e + a1o;
  float* orow = outg + ((size_t)bz * OHW + oi) * OHW + oj0;
  if (by != 0 && by != 15 && bxt != 0 && bxt != 7) {
    float2 o2; o2.x = v0; o2.y = v1;
    *(float2*)orow = o2;
  } else {
    // boundary rows/cols {0,1,255} are owned by dgp_aux (ran before us)
    if (oi >= 2 && oi != 255) {
      if (oj0 >= 2 && oj0 != 255) orow[0] = v0;
      const int oj1 = oj0 + 1;
      if (oj1 >= 2 && oj1 != 255) orow[1] = v1;
    }
  }
}

extern "C" void kernel_launch(void* const* d_in, const int* in_sizes, int n_in,
                              void* d_out, int out_size, void* d_ws, size_t ws_size,
                              hipStream_t stream) {
  const float* inp  = (const float*)d_in[0];
  const float* mtfp = (const float*)d_in[1];
  const int*   rp   = (const int*)d_in[2];
  const int*   cp   = (const int*)d_in[3];
  float* outg = (float*)d_out;
  _Float16* ckg = (_Float16*)d_ws;   // 32 * 640 halves = 40 KB

  hipLaunchKernelGGL(dgp_aux, dim3(704), dim3(128), 0, stream,
                     inp, mtfp, rp, cp, ckg, outg);
  hipLaunchKernelGGL(dgp_main, dim3(OHW / TW, OHW / TH, 32), dim3(NTHREADS), 0, stream,
                     inp, rp, cp, (const _Float16*)ckg, outg);
}

// Round 16
// 270.692 us; speedup vs baseline: 1.3785x; 1.3785x over previous
//
#include <hip/hip_runtime.h>

typedef _Float16 half2v __attribute__((ext_vector_type(2)));
typedef _Float16 half4v __attribute__((ext_vector_type(4)));
typedef _Float16 half8v __attribute__((ext_vector_type(8)));

#define HH 1024
#define OHW 256
#define TH 16
#define TW 32
#define NR 80        // input-tile rows
#define NCH 18       // data chunks (8 halves) per row = 144 cols
#define ROWH 160     // padded row stride in halves (20 chunks)
#define NTHREADS 256
#define ESPAN 528
#define ECHUNK (ESPAN/4)

#if defined(__has_builtin)
#  if __has_builtin(__builtin_amdgcn_fdot2)
#    define HAS_FDOT2 1
#  endif
#endif
#ifndef HAS_FDOT2
#  define HAS_FDOT2 0
#endif

__constant__ float DEC12c[12] = {
  -1.20162964e-04f,  1.615524292e-03f, -1.0385513306e-02f,  4.3619155884e-02f,
  -1.45397186478e-01f, 6.10668182370e-01f, 6.10668182370e-01f, -1.45397186478e-01f,
   4.3619155884e-02f, -1.0385513306e-02f,  1.615524292e-03f, -1.20162964e-04f
};

__device__ __forceinline__ int clampi(int v) { return v < 0 ? 0 : (v > HH - 1 ? HH - 1 : v); }

__device__ __forceinline__ int swzc(int c, int r) {
  return c ^ ((c >> 3) & 1) ^ ((r >> 2) & 3);
}

__device__ __forceinline__ half2v mk2(_Float16 a, _Float16 b) {
  half2v r; r.x = a; r.y = b; return r;
}

template<int J>   // J = half2 index 0..11 within 3 half8 regs
__device__ __forceinline__ half2v sel3(half8v a, half8v b, half8v c) {
  constexpr int V = J >> 2, E = J & 3;
  const half8v s = (V == 0) ? a : (V == 1) ? b : c;
  return mk2(s[2 * E], s[2 * E + 1]);
}
template<int E>
__device__ __forceinline__ half2v g2(half8v v) { return mk2(v[2 * E], v[2 * E + 1]); }

__device__ __forceinline__ float dot2acc(half2v w, half2v k, float acc) {
#if HAS_FDOT2
  return __builtin_amdgcn_fdot2(w, k, acc, false);
#else
  return acc + (float)w.x * (float)k.x + (float)w.y * (float)k.y;
#endif
}

// =================== aux kernel: ckbuild + edgefix + cornerfix ===================
// grid.x = 32 (ckbuild) + 384 (edgefix) + 288 (cornerfix) = 704, block 128
// Edge sections SKIP the 9 corner points per image; cornerfix blocks own them
// exclusively (no intra-dispatch write races — blocks are unordered).
__global__ __launch_bounds__(128) void dgp_aux(
    const float* __restrict__ inp, const float* __restrict__ mtfp,
    const int* __restrict__ rp, const int* __restrict__ cp,
    _Float16* __restrict__ ckg, float* __restrict__ outg) {
  __shared__ __align__(16) unsigned char smem[45056];
  float* tile = (float*)smem;                          // 20*528 f32 = 42240 B
  float* ck   = (float*)(smem + 42240);                // 400 f32
  float* kva  = (float*)(smem + 42240 + 1600);         // 180 f32
  float* mlds = (float*)(smem + 42240 + 1600 + 720);   // 81 f32
  float* avs  = (float*)(smem + 42240 + 1600 + 720 + 324);        // 12
  float* bvs  = (float*)(smem + 42240 + 1600 + 720 + 324 + 48);   // 12

  const int tid = threadIdx.x;
  const int b = blockIdx.x;

  if (b < 32) {
    // ---------------- section 1: combined-kernel build -> ckg ----------------
    const int bz = b;
    const int chC = bz & 7;
    const int rv = rp[bz], cv = cp[bz];
    const int rf = rv & 1, cf = cv & 1;

    if (tid < 12)       avs[tid] = rf ? DEC12c[tid] : (tid == 6 ? 1.f : 0.f);
    else if (tid < 24)  bvs[tid - 12] = cf ? DEC12c[tid - 12] : (tid - 12 == 6 ? 1.f : 0.f);
    else if (tid < 105) { const int m = tid - 24; mlds[m] = mtfp[m * 8 + chC]; }
    __syncthreads();

    for (int i = tid; i < 180; i += 128) {
      const int S = i / 9, v = i - S * 9;
      const int plo = (S - 8 > 0) ? S - 8 : 0, phi = (S < 11) ? S : 11;
      float s1 = 0.f;
      for (int p = plo; p <= phi; ++p) s1 += avs[p] * mlds[(S - p) * 9 + v];
      kva[i] = s1;
    }
    __syncthreads();

    half2v* out2 = (half2v*)ckg;
    for (int i = tid; i < 200; i += 128) {
      const int S = i / 10, m = i - S * 10;
      float s[2];
      #pragma unroll
      for (int h = 0; h < 2; ++h) {
        const int T = 2 * m + h;
        const int qlo = (T - 8 > 0) ? T - 8 : 0, qhi = (T < 11) ? T : 11;
        float acc = 0.f;
        for (int q = qlo; q <= qhi; ++q) acc += bvs[q] * kva[S * 9 + (T - q)];
        s[h] = acc;
      }
      out2[bz * 320 + S * 16 + m] = mk2((_Float16)s[0], (_Float16)s[1]);
    }
  } else if (b < 416) {
    // ---------------- section 2: edge fixup (rows/cols {0,1,255}, minus corners) ----------------
    const int e = b - 32;
    const int bx = e & 1;
    const int t = e >> 1;
    const int segi6 = t % 6;
    const int bz = t / 6;
    const bool isRow = (segi6 < 3);
    const int segi = isRow ? segi6 : segi6 - 3;
    const int fixedo = (segi == 2) ? 255 : segi;
    const int chC = bz & 7;
    const int rv = rp[bz], cv = cp[bz];
    const int ri = rv >> 1, rf = rv & 1, ci = cv >> 1, cf = cv & 1;

    if (tid < 12) {
      float av = rf ? DEC12c[tid] : (tid == 6 ? 1.f : 0.f);
      if (isRow) {
        const int xi = (2 + 4 * fixedo - ri) - 6 + tid;
        if (xi < 0 || xi >= HH) av = 0.f;
      }
      avs[tid] = av;
    } else if (tid < 24) {
      const int q = tid - 12;
      float bv = cf ? DEC12c[q] : (q == 6 ? 1.f : 0.f);
      if (!isRow) {
        const int xj = (2 + 4 * fixedo - ci) - 6 + q;
        if (xj < 0 || xj >= HH) bv = 0.f;
      }
      bvs[q] = bv;
    } else if (tid < 105) {
      const int m = tid - 24; mlds[m] = mtfp[m * 8 + chC];
    }
    __syncthreads();

    for (int i = tid; i < 180; i += 128) {
      const int S = i / 9, v = i - S * 9;
      const int plo = (S - 8 > 0) ? S - 8 : 0, phi = (S < 11) ? S : 11;
      float s1 = 0.f;
      for (int p = plo; p <= phi; ++p) s1 += avs[p] * mlds[(S - p) * 9 + v];
      kva[i] = s1;
    }
    __syncthreads();
    for (int i = tid; i < 400; i += 128) {
      const int S = i / 20, T = i - S * 20;
      const int qlo = (T - 8 > 0) ? T - 8 : 0, qhi = (T < 11) ? T : 11;
      float s1 = 0.f;
      for (int q = qlo; q <= qhi; ++q) s1 += bvs[q] * kva[S * 9 + (T - q)];
      ck[i] = s1;
    }

    const float* src = inp + ((size_t)bz << 20);
    if (isRow) {
      const int R0 = (2 + 4 * fixedo - ri) - 10;
      const int C0c = 512 * bx - 8 - ci;
      for (int i = tid; i < 20 * ECHUNK; i += 128) {
        const int rr = i / ECHUNK, jc = i - rr * ECHUNK;
        const float* grow = src + (clampi(R0 + rr) << 10);
        const int c0 = C0c + 4 * jc;
        float4 v;
        v.x = grow[clampi(c0 + 0)];
        v.y = grow[clampi(c0 + 1)];
        v.z = grow[clampi(c0 + 2)];
        v.w = grow[clampi(c0 + 3)];
        *(float4*)(tile + rr * ESPAN + 4 * jc) = v;
      }
    } else {
      const int Cw0 = (2 + 4 * fixedo - ci) - 10;
      const int Rr0 = 512 * bx - 8 - ri;
      for (int i = tid; i < 20 * ESPAN; i += 128) {
        const int T = i / ESPAN, rr = i - T * ESPAN;
        tile[T * ESPAN + rr] = src[(clampi(Rr0 + rr) << 10) + clampi(Cw0 + T)];
      }
    }
    __syncthreads();

    float acc = 0.f;
    #pragma unroll 4
    for (int L = 0; L < 20; ++L) {
      const float* wp = tile + L * ESPAN + 4 * tid;
      float w[20];
      #pragma unroll
      for (int j = 0; j < 5; ++j) {
        const float4 v = *(const float4*)(wp + 4 * j);
        w[4 * j] = v.x; w[4 * j + 1] = v.y; w[4 * j + 2] = v.z; w[4 * j + 3] = v.w;
      }
      if (isRow) {
        #pragma unroll
        for (int ee = 0; ee < 20; ++ee) acc += ck[L * 20 + ee] * w[ee];
      } else {
        #pragma unroll
        for (int ee = 0; ee < 20; ++ee) acc += ck[ee * 20 + L] * w[ee];
      }
    }

    int oi, oj;
    if (isRow) { oi = fixedo; oj = 128 * bx + tid; }
    else       { oj = fixedo; oi = 128 * bx + tid; }
    const int ov = isRow ? oj : oi;   // the varying coordinate
    if (ov != 0 && ov != 1 && ov != 255)   // corners owned by cornerfix blocks
      outg[((size_t)bz * OHW + oi) * OHW + oj] = acc;
  } else {
    // ---------------- section 3: corner fixup (9 points/image) ----------------
    const int c = b - 416;
    const int bi = c % 3;
    const int t = c / 3;
    const int bj = t % 3;
    const int bz = t / 3;
    const int oi = (bi == 2) ? 255 : bi;
    const int oj = (bj == 2) ? 255 : bj;
    const int chC = bz & 7;
    const int rv = rp[bz], cv = cp[bz];
    const int ri = rv >> 1, rf = rv & 1, ci = cv >> 1, cf = cv & 1;

    if (tid < 12)       avs[tid] = rf ? DEC12c[tid] : (tid == 6 ? 1.f : 0.f);
    else if (tid < 24)  bvs[tid - 12] = cf ? DEC12c[tid - 12] : (tid - 12 == 6 ? 1.f : 0.f);
    for (int m = tid; m < 81; m += 128) mlds[m] = mtfp[m * 8 + chC];
    __syncthreads();
    if (tid >= 64) return;

    const int Ri = 2 + 4 * oi - ri;
    const int Cj = 2 + 4 * oj - ci;
    const float* src = inp + ((size_t)bz << 20);

    float acc = 0.f;
    for (int pair = tid; pair < 144; pair += 64) {
      const int p = pair / 12, q = pair - 12 * (pair / 12);
      const int xi = Ri - 6 + p, xj = Cj - 6 + q;
      if (xi < 0 || xi >= HH || xj < 0 || xj >= HH) continue;
      const float ab = avs[p] * bvs[q];
      if (ab == 0.f) continue;
      float s = 0.f;
      #pragma unroll
      for (int u = 0; u < 9; ++u) {
        const float* grow = src + (clampi(xi - 4 + u) << 10);
        #pragma unroll
        for (int v = 0; v < 9; ++v) s += mlds[u * 9 + v] * grow[clampi(xj - 4 + v)];
      }
      acc += ab * s;
    }
    #pragma unroll
    for (int off = 32; off > 0; off >>= 1) acc += __shfl_down(acc, off);
    if (tid == 0) outg[((size_t)bz * OHW + oi) * OHW + oj] = acc;
  }
}

// =================== main kernel: launch_bounds(256,4) — 64-VGPR cap, no spill ===================
// (r15's (256,6) forced a 40-VGPR cap; the epilogue guard overflowed it and the
//  allocator spilled loop-carried DOT_STEP values -> 1.15 GB scratch traffic.)
__global__ __launch_bounds__(NTHREADS, 4) void dgp_main(
    const float* __restrict__ inp, const int* __restrict__ rp,
    const int* __restrict__ cp, const _Float16* __restrict__ ckg,
    float* __restrict__ outg) {
  __shared__ __align__(64) _Float16 tile[NR * ROWH];   // 25600 B

  const int tid = threadIdx.x;
  const int bxt = blockIdx.x, by = blockIdx.y, bz = blockIdx.z;
  const int rv = rp[bz], cv = cp[bz];
  const int ri = rv >> 1, ci = cv >> 1;
  const int R0 = 4 * TH * by - 8 - ri;
  const int C0 = 4 * TW * bxt - 8 - ci;

  // stage 80x144 tile as f16, swizzled chunks; per-chunk interior fast path
  const float* src = inp + ((size_t)bz << 20);
  for (int idx = tid; idx < NR * NCH; idx += NTHREADS) {
    const int rr = idx / 18, g = idx - 18 * rr;
    const float* grow = src + (clampi(R0 + rr) << 10);
    const int c0 = C0 + 8 * g;
    float v[8];
    if (c0 >= 0 && c0 + 7 <= HH - 1) {
      __builtin_memcpy(v, grow + c0, 32);
    } else {
      #pragma unroll
      for (int i = 0; i < 8; ++i) v[i] = grow[clampi(c0 + i)];
    }
    _Float16 h[8];
    #pragma unroll
    for (int i = 0; i < 8; ++i) h[i] = (_Float16)v[i];
    __builtin_memcpy(tile + rr * ROWH + (swzc(g, rr) << 3), h, 16);
  }
  __syncthreads();

  const int ty = tid >> 4;   // 0..15 output row
  const int tx = tid & 15;   // 0..15 -> 2 outputs at cols 2tx, 2tx+1
  const int rbase = 4 * ty;
  const size_t kbase = (size_t)bz * 640;

  float a0e = 0.f, a0o = 0.f, a1e = 0.f, a1o = 0.f;

#define DOT_STEP(s_) do {                                                \
    const int r_ = rbase + (s_);                                         \
    const _Float16* rp_ = tile + r_ * ROWH;                              \
    const half8v w0 = *(const half8v*)(rp_ + (swzc(tx + 0, r_) << 3));   \
    const half8v w1 = *(const half8v*)(rp_ + (swzc(tx + 1, r_) << 3));   \
    const half8v w2 = *(const half8v*)(rp_ + (swzc(tx + 2, r_) << 3));   \
    const _Float16* kp_ = ckg + kbase + (s_) * 32;                       \
    const half8v K0 = *(const half8v*)(kp_);                             \
    const half8v K1 = *(const half8v*)(kp_ + 8);                         \
    const half4v K2 = *(const half4v*)(kp_ + 16);                        \
    a0e = dot2acc(sel3<0>(w0, w1, w2), g2<0>(K0), a0e);                  \
    a0o = dot2acc(sel3<1>(w0, w1, w2), g2<1>(K0), a0o);                  \
    a0e = dot2acc(sel3<2>(w0, w1, w2), g2<2>(K0), a0e);                  \
    a0o = dot2acc(sel3<3>(w0, w1, w2), g2<3>(K0), a0o);                  \
    a0e = dot2acc(sel3<4>(w0, w1, w2), g2<0>(K1), a0e);                  \
    a0o = dot2acc(sel3<5>(w0, w1, w2), g2<1>(K1), a0o);                  \
    a0e = dot2acc(sel3<6>(w0, w1, w2), g2<2>(K1), a0e);                  \
    a0o = dot2acc(sel3<7>(w0, w1, w2), g2<3>(K1), a0o);                  \
    a0e = dot2acc(sel3<8>(w0, w1, w2), mk2(K2[0], K2[1]), a0e);          \
    a0o = dot2acc(sel3<9>(w0, w1, w2), mk2(K2[2], K2[3]), a0o);          \
    a1e = dot2acc(sel3<2>(w0, w1, w2), g2<0>(K0), a1e);                  \
    a1o = dot2acc(sel3<3>(w0, w1, w2), g2<1>(K0), a1o);                  \
    a1e = dot2acc(sel3<4>(w0, w1, w2), g2<2>(K0), a1e);                  \
    a1o = dot2acc(sel3<5>(w0, w1, w2), g2<3>(K0), a1o);                  \
    a1e = dot2acc(sel3<6>(w0, w1, w2), g2<0>(K1), a1e);                  \
    a1o = dot2acc(sel3<7>(w0, w1, w2), g2<1>(K1), a1o);                  \
    a1e = dot2acc(sel3<8>(w0, w1, w2), g2<2>(K1), a1e);                  \
    a1o = dot2acc(sel3<9>(w0, w1, w2), g2<3>(K1), a1o);                  \
    a1e = dot2acc(sel3<10>(w0, w1, w2), mk2(K2[0], K2[1]), a1e);         \
    a1o = dot2acc(sel3<11>(w0, w1, w2), mk2(K2[2], K2[3]), a1o);         \
  } while (0)

  DOT_STEP(0);  DOT_STEP(1);  DOT_STEP(2);  DOT_STEP(3);  DOT_STEP(4);
  DOT_STEP(5);  DOT_STEP(6);  DOT_STEP(7);  DOT_STEP(8);  DOT_STEP(9);
  DOT_STEP(10); DOT_STEP(11); DOT_STEP(12); DOT_STEP(13); DOT_STEP(14);
  DOT_STEP(15); DOT_STEP(16); DOT_STEP(17); DOT_STEP(18); DOT_STEP(19);
#undef DOT_STEP

  const int oi = TH * by + ty;
  const int oj0 = TW * bxt + 2 * tx;
  const float v0 = a0e + a0o;
  const float v1 = a1e + a1o;
  float* orow = outg + ((size_t)bz * OHW + oi) * OHW + oj0;
  if (by != 0 && by != 15 && bxt != 0 && bxt != 7) {
    float2 o2; o2.x = v0; o2.y = v1;
    *(float2*)orow = o2;
  } else {
    // boundary rows/cols {0,1,255} are owned by dgp_aux (ran before us)
    if (oi >= 2 && oi != 255) {
      if (oj0 >= 2 && oj0 != 255) orow[0] = v0;
      const int oj1 = oj0 + 1;
      if (oj1 >= 2 && oj1 != 255) orow[1] = v1;
    }
  }
}

extern "C" void kernel_launch(void* const* d_in, const int* in_sizes, int n_in,
                              void* d_out, int out_size, void* d_ws, size_t ws_size,
                              hipStream_t stream) {
  const float* inp  = (const float*)d_in[0];
  const float* mtfp = (const float*)d_in[1];
  const int*   rp   = (const int*)d_in[2];
  const int*   cp   = (const int*)d_in[3];
  float* outg = (float*)d_out;
  _Float16* ckg = (_Float16*)d_ws;   // 32 * 640 halves = 40 KB

  hipLaunchKernelGGL(dgp_aux, dim3(704), dim3(128), 0, stream,
                     inp, mtfp, rp, cp, ckg, outg);
  hipLaunchKernelGGL(dgp_main, dim3(OHW / TW, OHW / TH, 32), dim3(NTHREADS), 0, stream,
                     inp, rp, cp, (const _Float16*)ckg, outg);
}

// Round 17
// 116.723 us; speedup vs baseline: 3.1968x; 2.3191x over previous
//
#include <hip/hip_runtime.h>

typedef _Float16 half2v __attribute__((ext_vector_type(2)));
typedef _Float16 half4v __attribute__((ext_vector_type(4)));
typedef _Float16 half8v __attribute__((ext_vector_type(8)));

#define HH 1024
#define OHW 256
#define TH 16
#define TW 32
#define NR 80        // input-tile rows
#define NCH 18       // data chunks (8 halves) per row = 144 cols
#define ROWH 160     // padded row stride in halves (20 chunks)
#define NTHREADS 256
#define ESPAN 528
#define ECHUNK (ESPAN/4)

#if defined(__has_builtin)
#  if __has_builtin(__builtin_amdgcn_fdot2)
#    define HAS_FDOT2 1
#  endif
#endif
#ifndef HAS_FDOT2
#  define HAS_FDOT2 0
#endif

__constant__ float DEC12c[12] = {
  -1.20162964e-04f,  1.615524292e-03f, -1.0385513306e-02f,  4.3619155884e-02f,
  -1.45397186478e-01f, 6.10668182370e-01f, 6.10668182370e-01f, -1.45397186478e-01f,
   4.3619155884e-02f, -1.0385513306e-02f,  1.615524292e-03f, -1.20162964e-04f
};

__device__ __forceinline__ int clampi(int v) { return v < 0 ? 0 : (v > HH - 1 ? HH - 1 : v); }

__device__ __forceinline__ int swzc(int c, int r) {
  return c ^ ((c >> 3) & 1) ^ ((r >> 2) & 3);
}

__device__ __forceinline__ half2v mk2(_Float16 a, _Float16 b) {
  half2v r; r.x = a; r.y = b; return r;
}

template<int J>   // J = half2 index 0..11 within 3 half8 regs
__device__ __forceinline__ half2v sel3(half8v a, half8v b, half8v c) {
  constexpr int V = J >> 2, E = J & 3;
  const half8v s = (V == 0) ? a : (V == 1) ? b : c;
  return mk2(s[2 * E], s[2 * E + 1]);
}
template<int E>
__device__ __forceinline__ half2v g2(half8v v) { return mk2(v[2 * E], v[2 * E + 1]); }

__device__ __forceinline__ float dot2acc(half2v w, half2v k, float acc) {
#if HAS_FDOT2
  return __builtin_amdgcn_fdot2(w, k, acc, false);
#else
  return acc + (float)w.x * (float)k.x + (float)w.y * (float)k.y;
#endif
}

// =================== aux kernel: ckbuild + edgefix + cornerfix ===================
// grid.x = 32 (ckbuild) + 384 (edgefix) + 288 (cornerfix) = 704, block 128
// Edge sections SKIP the 9 corner points per image; cornerfix blocks own them
// exclusively (no intra-dispatch write races — blocks are unordered).
__global__ __launch_bounds__(128) void dgp_aux(
    const float* __restrict__ inp, const float* __restrict__ mtfp,
    const int* __restrict__ rp, const int* __restrict__ cp,
    _Float16* __restrict__ ckg, float* __restrict__ outg) {
  __shared__ __align__(16) unsigned char smem[45056];
  float* tile = (float*)smem;                          // 20*528 f32 = 42240 B
  float* ck   = (float*)(smem + 42240);                // 400 f32
  float* kva  = (float*)(smem + 42240 + 1600);         // 180 f32
  float* mlds = (float*)(smem + 42240 + 1600 + 720);   // 81 f32
  float* avs  = (float*)(smem + 42240 + 1600 + 720 + 324);        // 12
  float* bvs  = (float*)(smem + 42240 + 1600 + 720 + 324 + 48);   // 12

  const int tid = threadIdx.x;
  const int b = blockIdx.x;

  if (b < 32) {
    // ---------------- section 1: combined-kernel build -> ckg ----------------
    const int bz = b;
    const int chC = bz & 7;
    const int rv = rp[bz], cv = cp[bz];
    const int rf = rv & 1, cf = cv & 1;

    if (tid < 12)       avs[tid] = rf ? DEC12c[tid] : (tid == 6 ? 1.f : 0.f);
    else if (tid < 24)  bvs[tid - 12] = cf ? DEC12c[tid - 12] : (tid - 12 == 6 ? 1.f : 0.f);
    else if (tid < 105) { const int m = tid - 24; mlds[m] = mtfp[m * 8 + chC]; }
    __syncthreads();

    for (int i = tid; i < 180; i += 128) {
      const int S = i / 9, v = i - S * 9;
      const int plo = (S - 8 > 0) ? S - 8 : 0, phi = (S < 11) ? S : 11;
      float s1 = 0.f;
      for (int p = plo; p <= phi; ++p) s1 += avs[p] * mlds[(S - p) * 9 + v];
      kva[i] = s1;
    }
    __syncthreads();

    half2v* out2 = (half2v*)ckg;
    for (int i = tid; i < 200; i += 128) {
      const int S = i / 10, m = i - S * 10;
      float s[2];
      #pragma unroll
      for (int h = 0; h < 2; ++h) {
        const int T = 2 * m + h;
        const int qlo = (T - 8 > 0) ? T - 8 : 0, qhi = (T < 11) ? T : 11;
        float acc = 0.f;
        for (int q = qlo; q <= qhi; ++q) acc += bvs[q] * kva[S * 9 + (T - q)];
        s[h] = acc;
      }
      out2[bz * 320 + S * 16 + m] = mk2((_Float16)s[0], (_Float16)s[1]);
    }
  } else if (b < 416) {
    // ---------------- section 2: edge fixup (rows/cols {0,1,255}, minus corners) ----------------
    const int e = b - 32;
    const int bx = e & 1;
    const int t = e >> 1;
    const int segi6 = t % 6;
    const int bz = t / 6;
    const bool isRow = (segi6 < 3);
    const int segi = isRow ? segi6 : segi6 - 3;
    const int fixedo = (segi == 2) ? 255 : segi;
    const int chC = bz & 7;
    const int rv = rp[bz], cv = cp[bz];
    const int ri = rv >> 1, rf = rv & 1, ci = cv >> 1, cf = cv & 1;

    if (tid < 12) {
      float av = rf ? DEC12c[tid] : (tid == 6 ? 1.f : 0.f);
      if (isRow) {
        const int xi = (2 + 4 * fixedo - ri) - 6 + tid;
        if (xi < 0 || xi >= HH) av = 0.f;
      }
      avs[tid] = av;
    } else if (tid < 24) {
      const int q = tid - 12;
      float bv = cf ? DEC12c[q] : (q == 6 ? 1.f : 0.f);
      if (!isRow) {
        const int xj = (2 + 4 * fixedo - ci) - 6 + q;
        if (xj < 0 || xj >= HH) bv = 0.f;
      }
      bvs[q] = bv;
    } else if (tid < 105) {
      const int m = tid - 24; mlds[m] = mtfp[m * 8 + chC];
    }
    __syncthreads();

    for (int i = tid; i < 180; i += 128) {
      const int S = i / 9, v = i - S * 9;
      const int plo = (S - 8 > 0) ? S - 8 : 0, phi = (S < 11) ? S : 11;
      float s1 = 0.f;
      for (int p = plo; p <= phi; ++p) s1 += avs[p] * mlds[(S - p) * 9 + v];
      kva[i] = s1;
    }
    __syncthreads();
    for (int i = tid; i < 400; i += 128) {
      const int S = i / 20, T = i - S * 20;
      const int qlo = (T - 8 > 0) ? T - 8 : 0, qhi = (T < 11) ? T : 11;
      float s1 = 0.f;
      for (int q = qlo; q <= qhi; ++q) s1 += bvs[q] * kva[S * 9 + (T - q)];
      ck[i] = s1;
    }

    const float* src = inp + ((size_t)bz << 20);
    if (isRow) {
      const int R0 = (2 + 4 * fixedo - ri) - 10;
      const int C0c = 512 * bx - 8 - ci;
      for (int i = tid; i < 20 * ECHUNK; i += 128) {
        const int rr = i / ECHUNK, jc = i - rr * ECHUNK;
        const float* grow = src + (clampi(R0 + rr) << 10);
        const int c0 = C0c + 4 * jc;
        float4 v;
        v.x = grow[clampi(c0 + 0)];
        v.y = grow[clampi(c0 + 1)];
        v.z = grow[clampi(c0 + 2)];
        v.w = grow[clampi(c0 + 3)];
        *(float4*)(tile + rr * ESPAN + 4 * jc) = v;
      }
    } else {
      const int Cw0 = (2 + 4 * fixedo - ci) - 10;
      const int Rr0 = 512 * bx - 8 - ri;
      for (int i = tid; i < 20 * ESPAN; i += 128) {
        const int T = i / ESPAN, rr = i - T * ESPAN;
        tile[T * ESPAN + rr] = src[(clampi(Rr0 + rr) << 10) + clampi(Cw0 + T)];
      }
    }
    __syncthreads();

    float acc = 0.f;
    #pragma unroll 4
    for (int L = 0; L < 20; ++L) {
      const float* wp = tile + L * ESPAN + 4 * tid;
      float w[20];
      #pragma unroll
      for (int j = 0; j < 5; ++j) {
        const float4 v = *(const float4*)(wp + 4 * j);
        w[4 * j] = v.x; w[4 * j + 1] = v.y; w[4 * j + 2] = v.z; w[4 * j + 3] = v.w;
      }
      if (isRow) {
        #pragma unroll
        for (int ee = 0; ee < 20; ++ee) acc += ck[L * 20 + ee] * w[ee];
      } else {
        #pragma unroll
        for (int ee = 0; ee < 20; ++ee) acc += ck[ee * 20 + L] * w[ee];
      }
    }

    int oi, oj;
    if (isRow) { oi = fixedo; oj = 128 * bx + tid; }
    else       { oj = fixedo; oi = 128 * bx + tid; }
    const int ov = isRow ? oj : oi;   // the varying coordinate
    if (ov != 0 && ov != 1 && ov != 255)   // corners owned by cornerfix blocks
      outg[((size_t)bz * OHW + oi) * OHW + oj] = acc;
  } else {
    // ---------------- section 3: corner fixup (9 points/image) ----------------
    const int c = b - 416;
    const int bi = c % 3;
    const int t = c / 3;
    const int bj = t % 3;
    const int bz = t / 3;
    const int oi = (bi == 2) ? 255 : bi;
    const int oj = (bj == 2) ? 255 : bj;
    const int chC = bz & 7;
    const int rv = rp[bz], cv = cp[bz];
    const int ri = rv >> 1, rf = rv & 1, ci = cv >> 1, cf = cv & 1;

    if (tid < 12)       avs[tid] = rf ? DEC12c[tid] : (tid == 6 ? 1.f : 0.f);
    else if (tid < 24)  bvs[tid - 12] = cf ? DEC12c[tid - 12] : (tid - 12 == 6 ? 1.f : 0.f);
    for (int m = tid; m < 81; m += 128) mlds[m] = mtfp[m * 8 + chC];
    __syncthreads();
    if (tid >= 64) return;

    const int Ri = 2 + 4 * oi - ri;
    const int Cj = 2 + 4 * oj - ci;
    const float* src = inp + ((size_t)bz << 20);

    float acc = 0.f;
    for (int pair = tid; pair < 144; pair += 64) {
      const int p = pair / 12, q = pair - 12 * (pair / 12);
      const int xi = Ri - 6 + p, xj = Cj - 6 + q;
      if (xi < 0 || xi >= HH || xj < 0 || xj >= HH) continue;
      const float ab = avs[p] * bvs[q];
      if (ab == 0.f) continue;
      float s = 0.f;
      #pragma unroll
      for (int u = 0; u < 9; ++u) {
        const float* grow = src + (clampi(xi - 4 + u) << 10);
        #pragma unroll
        for (int v = 0; v < 9; ++v) s += mlds[u * 9 + v] * grow[clampi(xj - 4 + v)];
      }
      acc += ab * s;
    }
    #pragma unroll
    for (int off = 32; off > 0; off >>= 1) acc += __shfl_down(acc, off);
    if (tid == 0) outg[((size_t)bz * OHW + oi) * OHW + oj] = acc;
  }
}

// =================== main kernel: uncapped VGPR + branchless redirect epilogue ===================
// r12's unconditional-store body fit in 40 VGPR spill-free; the r13+ branchy
// epilogue forced a control-flow join that blew past any cap. Here: no min-waves
// hint (no forced cap) and an address-select epilogue (straight-line codegen).
// Boundary outputs (rows/cols {0,1,255}, owned by dgp_aux) are redirected to a
// dump region in d_ws instead of being skipped.
__global__ __launch_bounds__(NTHREADS) void dgp_main(
    const float* __restrict__ inp, const int* __restrict__ rp,
    const int* __restrict__ cp, const _Float16* __restrict__ ckg,
    float* __restrict__ outg, float* __restrict__ dumpf) {
  __shared__ __align__(64) _Float16 tile[NR * ROWH];   // 25600 B

  const int tid = threadIdx.x;
  const int bxt = blockIdx.x, by = blockIdx.y, bz = blockIdx.z;
  const int rv = rp[bz], cv = cp[bz];
  const int ri = rv >> 1, ci = cv >> 1;
  const int R0 = 4 * TH * by - 8 - ri;
  const int C0 = 4 * TW * bxt - 8 - ci;

  // stage 80x144 tile as f16, swizzled chunks; per-chunk interior fast path
  const float* src = inp + ((size_t)bz << 20);
  for (int idx = tid; idx < NR * NCH; idx += NTHREADS) {
    const int rr = idx / 18, g = idx - 18 * rr;
    const float* grow = src + (clampi(R0 + rr) << 10);
    const int c0 = C0 + 8 * g;
    float v[8];
    if (c0 >= 0 && c0 + 7 <= HH - 1) {
      __builtin_memcpy(v, grow + c0, 32);
    } else {
      #pragma unroll
      for (int i = 0; i < 8; ++i) v[i] = grow[clampi(c0 + i)];
    }
    _Float16 h[8];
    #pragma unroll
    for (int i = 0; i < 8; ++i) h[i] = (_Float16)v[i];
    __builtin_memcpy(tile + rr * ROWH + (swzc(g, rr) << 3), h, 16);
  }
  __syncthreads();

  const int ty = tid >> 4;   // 0..15 output row
  const int tx = tid & 15;   // 0..15 -> 2 outputs at cols 2tx, 2tx+1
  const int rbase = 4 * ty;
  const size_t kbase = (size_t)bz * 640;

  float a0e = 0.f, a0o = 0.f, a1e = 0.f, a1o = 0.f;

#define DOT_STEP(s_) do {                                                \
    const int r_ = rbase + (s_);                                         \
    const _Float16* rp_ = tile + r_ * ROWH;                              \
    const half8v w0 = *(const half8v*)(rp_ + (swzc(tx + 0, r_) << 3));   \
    const half8v w1 = *(const half8v*)(rp_ + (swzc(tx + 1, r_) << 3));   \
    const half8v w2 = *(const half8v*)(rp_ + (swzc(tx + 2, r_) << 3));   \
    const _Float16* kp_ = ckg + kbase + (s_) * 32;                       \
    const half8v K0 = *(const half8v*)(kp_);                             \
    const half8v K1 = *(const half8v*)(kp_ + 8);                         \
    const half4v K2 = *(const half4v*)(kp_ + 16);                        \
    a0e = dot2acc(sel3<0>(w0, w1, w2), g2<0>(K0), a0e);                  \
    a0o = dot2acc(sel3<1>(w0, w1, w2), g2<1>(K0), a0o);                  \
    a0e = dot2acc(sel3<2>(w0, w1, w2), g2<2>(K0), a0e);                  \
    a0o = dot2acc(sel3<3>(w0, w1, w2), g2<3>(K0), a0o);                  \
    a0e = dot2acc(sel3<4>(w0, w1, w2), g2<0>(K1), a0e);                  \
    a0o = dot2acc(sel3<5>(w0, w1, w2), g2<1>(K1), a0o);                  \
    a0e = dot2acc(sel3<6>(w0, w1, w2), g2<2>(K1), a0e);                  \
    a0o = dot2acc(sel3<7>(w0, w1, w2), g2<3>(K1), a0o);                  \
    a0e = dot2acc(sel3<8>(w0, w1, w2), mk2(K2[0], K2[1]), a0e);          \
    a0o = dot2acc(sel3<9>(w0, w1, w2), mk2(K2[2], K2[3]), a0o);          \
    a1e = dot2acc(sel3<2>(w0, w1, w2), g2<0>(K0), a1e);                  \
    a1o = dot2acc(sel3<3>(w0, w1, w2), g2<1>(K0), a1o);                  \
    a1e = dot2acc(sel3<4>(w0, w1, w2), g2<2>(K0), a1e);                  \
    a1o = dot2acc(sel3<5>(w0, w1, w2), g2<3>(K0), a1o);                  \
    a1e = dot2acc(sel3<6>(w0, w1, w2), g2<0>(K1), a1e);                  \
    a1o = dot2acc(sel3<7>(w0, w1, w2), g2<1>(K1), a1o);                  \
    a1e = dot2acc(sel3<8>(w0, w1, w2), g2<2>(K1), a1e);                  \
    a1o = dot2acc(sel3<9>(w0, w1, w2), g2<3>(K1), a1o);                  \
    a1e = dot2acc(sel3<10>(w0, w1, w2), mk2(K2[0], K2[1]), a1e);         \
    a1o = dot2acc(sel3<11>(w0, w1, w2), mk2(K2[2], K2[3]), a1o);         \
  } while (0)

  DOT_STEP(0);  DOT_STEP(1);  DOT_STEP(2);  DOT_STEP(3);  DOT_STEP(4);
  DOT_STEP(5);  DOT_STEP(6);  DOT_STEP(7);  DOT_STEP(8);  DOT_STEP(9);
  DOT_STEP(10); DOT_STEP(11); DOT_STEP(12); DOT_STEP(13); DOT_STEP(14);
  DOT_STEP(15); DOT_STEP(16); DOT_STEP(17); DOT_STEP(18); DOT_STEP(19);
#undef DOT_STEP

  const int oi = TH * by + ty;
  const int oj0 = TW * bxt + 2 * tx;
  const int oj1 = oj0 + 1;
  float* orow = outg + ((size_t)bz * OHW + oi) * OHW + oj0;
  float* dump = dumpf + tid;   // scratch sink, never read
  const bool rowbad = (oi < 2) | (oi == 255);
  float* d0 = (rowbad | (oj0 < 2) | (oj0 == 255)) ? dump : orow;
  float* d1 = (rowbad | (oj1 < 2) | (oj1 == 255)) ? dump : (orow + 1);
  *d0 = a0e + a0o;
  *d1 = a1e + a1o;
}

extern "C" void kernel_launch(void* const* d_in, const int* in_sizes, int n_in,
                              void* d_out, int out_size, void* d_ws, size_t ws_size,
                              hipStream_t stream) {
  const float* inp  = (const float*)d_in[0];
  const float* mtfp = (const float*)d_in[1];
  const int*   rp   = (const int*)d_in[2];
  const int*   cp   = (const int*)d_in[3];
  float* outg = (float*)d_out;
  _Float16* ckg = (_Float16*)d_ws;                          // 40 KB @ offset 0
  float* dumpf = (float*)((char*)d_ws + 49152);             // 1 KB dump sink

  hipLaunchKernelGGL(dgp_aux, dim3(704), dim3(128), 0, stream,
                     inp, mtfp, rp, cp, ckg, outg);
  hipLaunchKernelGGL(dgp_main, dim3(OHW / TW, OHW / TH, 32), dim3(NTHREADS), 0, stream,
                     inp, rp, cp, (const _Float16*)ckg, outg, dumpf);
}